// Round 1
// baseline (1341.878 us; speedup 1.0000x reference)
//
#include <hip/hip_runtime.h>
#include <hip/hip_bf16.h>
#include <float.h>

#define BN 4
#define NN 4096
#define DD 64
#define KK 16
#define KP1 17
#define NCHUNK 8
#define CHUNK (NN / NCHUNK)   // 512

// ---------------- kernel 0: per-point squared norm ----------------
__global__ __launch_bounds__(256) void k_sq(const float* __restrict__ x,
                                            float* __restrict__ sq) {
    int r = blockIdx.x * blockDim.x + threadIdx.x;          // 0..16383
    const float4* xr = reinterpret_cast<const float4*>(x + (size_t)r * DD);
    float a0 = 0.f, a1 = 0.f, a2 = 0.f, a3 = 0.f;
#pragma unroll
    for (int q = 0; q < 16; q++) {
        float4 v = xr[q];
        a0 += v.x * v.x; a1 += v.y * v.y; a2 += v.z * v.z; a3 += v.w * v.w;
    }
    sq[r] = (a0 + a1) + (a2 + a3);
}

// ---------------- kernel 1: chunked exact top-17 ----------------
// grid: (chunk=8, tile=16, b=4), block: 256 threads, thread = one query row.
__global__ __launch_bounds__(256) void k_knn_partial(
    const float* __restrict__ x, const float* __restrict__ sq,
    float* __restrict__ pvals, int* __restrict__ pidx) {
    const int chunk = blockIdx.x;
    const int tile  = blockIdx.y;
    const int b     = blockIdx.z;
    const int n     = tile * 256 + threadIdx.x;
    const int row   = b * NN + n;

    float xn[DD];
    const float4* xr = reinterpret_cast<const float4*>(x + (size_t)row * DD);
#pragma unroll
    for (int q = 0; q < 16; q++) {
        float4 v = xr[q];
        xn[4*q+0] = v.x; xn[4*q+1] = v.y; xn[4*q+2] = v.z; xn[4*q+3] = v.w;
    }
    const float sqn = sq[row];

    float vals[KP1]; int idxs[KP1];
#pragma unroll
    for (int i = 0; i < KP1; i++) { vals[i] = FLT_MAX; idxs[i] = 0x7fffffff; }
    float cm = FLT_MAX; int ci = 0x7fffffff;

    const int m0 = chunk * CHUNK;
    const float* xb  = x  + (size_t)b * NN * DD;
    const float* sqb = sq + (size_t)b * NN;

    for (int m = m0; m < m0 + CHUNK; m++) {
        const float4* xm = reinterpret_cast<const float4*>(xb + (size_t)m * DD);
        float a0 = 0.f, a1 = 0.f, a2 = 0.f, a3 = 0.f;
#pragma unroll
        for (int q = 0; q < 16; q++) {
            float4 w = xm[q];
            a0 += xn[4*q+0] * w.x; a1 += xn[4*q+1] * w.y;
            a2 += xn[4*q+2] * w.z; a3 += xn[4*q+3] * w.w;
        }
        float dot = (a0 + a1) + (a2 + a3);
        float d2  = (sqn + sqb[m]) - 2.0f * dot;
        // stream is in increasing m: on tie with current worst, incumbent
        // (smaller index) wins -> strict < is exactly top_k's tie rule here.
        if (d2 < cm) {
            bool done = false;
#pragma unroll
            for (int i = 0; i < KP1; i++) {         // evict the (cm,ci) element
                bool hit = (!done) && (vals[i] == cm) && (idxs[i] == ci);
                vals[i] = hit ? d2 : vals[i];
                idxs[i] = hit ? m  : idxs[i];
                done = done || hit;
            }
            cm = vals[0]; ci = idxs[0];             // rescan: max, ties -> larger idx
#pragma unroll
            for (int i = 1; i < KP1; i++) {
                bool g = (vals[i] > cm) || ((vals[i] == cm) && (idxs[i] > ci));
                cm = g ? vals[i] : cm;
                ci = g ? idxs[i] : ci;
            }
        }
    }
    float* pv = pvals + ((size_t)row * NCHUNK + chunk) * KP1;
    int*   pi = pidx  + ((size_t)row * NCHUNK + chunk) * KP1;
#pragma unroll
    for (int i = 0; i < KP1; i++) { pv[i] = vals[i]; pi[i] = idxs[i]; }
}

// ---------------- kernel 2: merge 8x17 partials -> sorted idx[1..16] ----------------
__global__ __launch_bounds__(256) void k_merge(
    const float* __restrict__ pvals, const int* __restrict__ pidx,
    int* __restrict__ knn_idx) {
    const int row = blockIdx.x * blockDim.x + threadIdx.x;  // 0..16383
    float vals[KP1]; int idxs[KP1];
#pragma unroll
    for (int i = 0; i < KP1; i++) { vals[i] = FLT_MAX; idxs[i] = 0x7fffffff; }
    float cm = FLT_MAX; int ci = 0x7fffffff;

    const float* pv = pvals + (size_t)row * NCHUNK * KP1;
    const int*   pi = pidx  + (size_t)row * NCHUNK * KP1;
    for (int t = 0; t < NCHUNK * KP1; t++) {
        float d2 = pv[t]; int m = pi[t];
        bool ins = (d2 < cm) || ((d2 == cm) && (m < ci));   // lexicographic
        if (ins) {
            bool done = false;
#pragma unroll
            for (int i = 0; i < KP1; i++) {
                bool hit = (!done) && (vals[i] == cm) && (idxs[i] == ci);
                vals[i] = hit ? d2 : vals[i];
                idxs[i] = hit ? m  : idxs[i];
                done = done || hit;
            }
            cm = vals[0]; ci = idxs[0];
#pragma unroll
            for (int i = 1; i < KP1; i++) {
                bool g = (vals[i] > cm) || ((vals[i] == cm) && (idxs[i] > ci));
                cm = g ? vals[i] : cm;
                ci = g ? idxs[i] : ci;
            }
        }
    }
    // ascending (val, idx) selection sort, fully unrolled
#pragma unroll
    for (int a = 0; a < KP1 - 1; a++) {
#pragma unroll
        for (int c = a + 1; c < KP1; c++) {
            bool sw = (vals[c] < vals[a]) || ((vals[c] == vals[a]) && (idxs[c] < idxs[a]));
            float tva = sw ? vals[c] : vals[a];
            float tvc = sw ? vals[a] : vals[c];
            vals[a] = tva; vals[c] = tvc;
            int tia = sw ? idxs[c] : idxs[a];
            int tic = sw ? idxs[a] : idxs[c];
            idxs[a] = tia; idxs[c] = tic;
        }
    }
#pragma unroll
    for (int q = 1; q < KP1; q++) knn_idx[(size_t)row * KK + (q - 1)] = idxs[q];
}

// ---------------- kernel 3: fused gather + MLP ----------------
// thread = one (b, n, k) point; weights transposed in LDS, broadcast reads.
__global__ __launch_bounds__(256) void k_mlp(
    const float* __restrict__ x, const int* __restrict__ knn_idx,
    const float* __restrict__ W1, const float* __restrict__ b1,
    const float* __restrict__ W2, const float* __restrict__ b2,
    float* __restrict__ out) {
    __shared__ float W1T[DD * DD];
    __shared__ float W2T[DD * DD];
    __shared__ float b1s[DD], b2s[DD];
    for (int i = threadIdx.x; i < DD * DD; i += blockDim.x) {
        int d = i >> 6, j = i & 63;
        W1T[j * DD + d] = W1[i];
        W2T[j * DD + d] = W2[i];
    }
    if (threadIdx.x < DD) {
        b1s[threadIdx.x] = b1[threadIdx.x];
        b2s[threadIdx.x] = b2[threadIdx.x];
    }
    __syncthreads();

    const int p = blockIdx.x * blockDim.x + threadIdx.x;    // 0..262143
    const int b = p >> 16;                                   // 65536 points per batch
    const int n = (p >> 4) & (NN - 1);
    const int m = knn_idx[p];

    const float4* xn4 = reinterpret_cast<const float4*>(x + ((size_t)b * NN + n) * DD);
    const float4* xm4 = reinterpret_cast<const float4*>(x + ((size_t)b * NN + m) * DD);
    float diff[DD];
#pragma unroll
    for (int q = 0; q < 16; q++) {
        float4 a = xn4[q], c = xm4[q];
        diff[4*q+0] = a.x - c.x; diff[4*q+1] = a.y - c.y;
        diff[4*q+2] = a.z - c.z; diff[4*q+3] = a.w - c.w;
    }

    float h[DD];
#pragma unroll
    for (int j = 0; j < DD; j++) {
        float acc = b1s[j];
#pragma unroll
        for (int d = 0; d < DD; d++) acc += diff[d] * W1T[j * DD + d];
        h[j] = acc > 0.f ? acc : 0.f;
    }

    float* op = out + (size_t)p * DD;
#pragma unroll
    for (int jq = 0; jq < 16; jq++) {
        float o[4];
#pragma unroll
        for (int u = 0; u < 4; u++) {
            int j = jq * 4 + u;
            float acc = b2s[j];
#pragma unroll
            for (int d = 0; d < DD; d++) acc += h[d] * W2T[j * DD + d];
            o[u] = acc;
        }
        float4 v; v.x = o[0]; v.y = o[1]; v.z = o[2]; v.w = o[3];
        reinterpret_cast<float4*>(op)[jq] = v;
    }
}

extern "C" void kernel_launch(void* const* d_in, const int* in_sizes, int n_in,
                              void* d_out, int out_size, void* d_ws, size_t ws_size,
                              hipStream_t stream) {
    const float* x  = (const float*)d_in[0];
    const float* W1 = (const float*)d_in[1];
    const float* b1 = (const float*)d_in[2];
    const float* W2 = (const float*)d_in[3];
    const float* b2 = (const float*)d_in[4];
    float* out = (float*)d_out;

    // ws: sq (16384 f) + knn_idx (262144 i) = 1.1 MB
    float* sq      = (float*)d_ws;
    int*   knn_idx = (int*)d_ws + BN * NN;
    // big transient partial lists live in d_out (consumed before k_mlp overwrites)
    float* pvals = out;                                     // 16384*8*17 floats
    int*   pidx  = (int*)out + (size_t)BN * NN * NCHUNK * KP1;

    k_sq<<<dim3(BN * NN / 256), dim3(256), 0, stream>>>(x, sq);
    k_knn_partial<<<dim3(NCHUNK, NN / 256, BN), dim3(256), 0, stream>>>(x, sq, pvals, pidx);
    k_merge<<<dim3(BN * NN / 256), dim3(256), 0, stream>>>(pvals, pidx, knn_idx);
    k_mlp<<<dim3(BN * NN * KK / 256), dim3(256), 0, stream>>>(x, knn_idx, W1, b1, W2, b2, out);
}